// Round 1
// baseline (209.956 us; speedup 1.0000x reference)
//
#include <hip/hip_runtime.h>

// CGA Cl(4,1) sandwich pipeline: out = decode( V * encode(x) * ~V ), per point.
// Memory-bound: 88 B/point * 2^21 = 184.5 MB -> ~29us floor at 6.3 TB/s.
// Sparse Cayley structure (80 + 80 nonzeros, signs +/-1) baked in at compile
// time via constexpr tables; #pragma unroll makes every index a literal so the
// whole contraction folds to register adds/subs (no dense 2560-FMA contraction,
// which would be compute-bound at ~68us).

namespace cga {

__host__ __device__ constexpr int popc5(int x) {
    int c = 0;
    for (int i = 0; i < 5; ++i) c += (x >> i) & 1;
    return c;
}

// i-th even-grade blade (ascending blade value), matching Python's _EVEN list.
__host__ __device__ constexpr int blade_of_even(int idx) {
    int cnt = 0;
    for (int b = 0; b < 32; ++b)
        if ((popc5(b) & 1) == 0) { if (cnt == idx) return b; ++cnt; }
    return 0;
}
__host__ __device__ constexpr int blade_of_odd(int idx) {
    int cnt = 0;
    for (int b = 0; b < 32; ++b)
        if ((popc5(b) & 1) == 1) { if (cnt == idx) return b; ++cnt; }
    return 0;
}
__host__ __device__ constexpr int even_index(int blade) {
    int idx = 0;
    for (int b = 0; b < blade; ++b) if ((popc5(b) & 1) == 0) ++idx;
    return idx;
}
__host__ __device__ constexpr int odd_index(int blade) {
    int idx = 0;
    for (int b = 0; b < blade; ++b) if ((popc5(b) & 1) == 1) ++idx;
    return idx;
}

// Sign of basis-blade product a*b (reorder sign + metric; e5 = bit4 squares -1).
__host__ __device__ constexpr int mul_sign(int a, int b) {
    int s = 0;
    for (int t = a >> 1; t; t >>= 1) s += popc5(t & b);
    int sign = (s & 1) ? -1 : 1;
    if ((a & b) & 16) sign = -sign;   // shared e5 factor squares to -1
    return sign;
}
__host__ __device__ constexpr int rev_sign(int b) {
    int g = popc5(b);
    return ((g * (g - 1) / 2) & 1) ? -1 : 1;
}

struct Tables {
    signed char t1_dst[16][5];  // odd-blade index of EVEN[ie] * G1[ip]
    signed char t1_sgn[16][5];
    signed char t2_e[16][5];    // even index e s.t. ODD[io] * EVEN[e] -> G1[iq]
    signed char t2_sgn[16][5];  // includes reverse sign of EVEN[e]
};

__host__ __device__ constexpr Tables make_tables() {
    Tables r{};
    for (int ie = 0; ie < 16; ++ie) {
        const int a = blade_of_even(ie);
        for (int ip = 0; ip < 5; ++ip) {
            const int b = 1 << ip;           // grade-1 blade
            const int c = a ^ b;             // odd result blade
            r.t1_dst[ie][ip] = (signed char)odd_index(c);
            r.t1_sgn[ie][ip] = (signed char)mul_sign(a, b);
        }
    }
    for (int io = 0; io < 16; ++io) {
        const int a = blade_of_odd(io);
        for (int iq = 0; iq < 5; ++iq) {
            const int c = 1 << iq;           // grade-1 target
            const int b = a ^ c;             // connecting blade: always even grade
            r.t2_e[io][iq]   = (signed char)even_index(b);
            r.t2_sgn[io][iq] = (signed char)(mul_sign(a, b) * rev_sign(b));
        }
    }
    return r;
}

constexpr Tables TAB = make_tables();

}  // namespace cga

__global__ __launch_bounds__(256) void cga_sandwich_kernel(
    const float* __restrict__ versor,
    const float* __restrict__ x,
    float* __restrict__ out,
    int n)
{
    const int i = blockIdx.x * blockDim.x + threadIdx.x;
    if (i >= n) return;

    // ---- load 16-component even versor via 4x float4 (64 B/thread) ----
    const float4* v4 = reinterpret_cast<const float4*>(versor) + (size_t)i * 4;
    const float4 a0 = v4[0], a1 = v4[1], a2 = v4[2], a3 = v4[3];
    const float v[16] = {a0.x, a0.y, a0.z, a0.w,
                         a1.x, a1.y, a1.z, a1.w,
                         a2.x, a2.y, a2.z, a2.w,
                         a3.x, a3.y, a3.z, a3.w};

    // ---- encode: P = (x, 0.5|x|^2 - 0.5, 0.5|x|^2 + 0.5) ----
    const float x0 = x[(size_t)3 * i + 0];
    const float x1 = x[(size_t)3 * i + 1];
    const float x2 = x[(size_t)3 * i + 2];
    const float hs = 0.5f * (x0 * x0 + x1 * x1 + x2 * x2);
    const float p[5] = {x0, x1, x2, hs - 0.5f, hs + 0.5f};

    // ---- mx = V * P  (even * grade1 -> odd, 80 signed FMAs) ----
    float mx[16];
#pragma unroll
    for (int o = 0; o < 16; ++o) mx[o] = 0.0f;
#pragma unroll
    for (int ie = 0; ie < 16; ++ie) {
#pragma unroll
        for (int ip = 0; ip < 5; ++ip) {
            const float s = (float)cga::TAB.t1_sgn[ie][ip];
            mx[cga::TAB.t1_dst[ie][ip]] += s * v[ie] * p[ip];
        }
    }

    // ---- q = mx * ~V  (odd * reversed-even -> grade-1, 80 signed FMAs) ----
    float q[5] = {0.0f, 0.0f, 0.0f, 0.0f, 0.0f};
#pragma unroll
    for (int io = 0; io < 16; ++io) {
#pragma unroll
        for (int iq = 0; iq < 5; ++iq) {
            const float s = (float)cga::TAB.t2_sgn[io][iq];
            q[iq] += s * mx[io] * v[cga::TAB.t2_e[io][iq]];
        }
    }

    // ---- decode: scale = q[e5] - q[e4]; out = q_xyz / scale ----
    const float scale = q[4] - q[3];
    const float inv = 1.0f / scale;
    out[(size_t)3 * i + 0] = q[0] * inv;
    out[(size_t)3 * i + 1] = q[1] * inv;
    out[(size_t)3 * i + 2] = q[2] * inv;
}

extern "C" void kernel_launch(void* const* d_in, const int* in_sizes, int n_in,
                              void* d_out, int out_size, void* d_ws, size_t ws_size,
                              hipStream_t stream) {
    const float* versor = (const float*)d_in[0];  // (N, 16) fp32
    const float* x      = (const float*)d_in[1];  // (N, 3)  fp32
    float* out          = (float*)d_out;          // (N, 3)  fp32
    const int n = in_sizes[0] / 16;

    const int block = 256;
    const int grid  = (n + block - 1) / block;
    cga_sandwich_kernel<<<grid, block, 0, stream>>>(versor, x, out, n);
}

// Round 2
// 209.930 us; speedup vs baseline: 1.0001x; 1.0001x over previous
//
#include <hip/hip_runtime.h>
#include <utility>

// CGA Cl(4,1) sandwich pipeline: out = decode( V * encode(x) * ~V ), per point.
// Memory-bound floor: 88 B/point * 2^21 = 184.5 MB -> ~29us at 6.3 TB/s.
//
// R2 change: the R1 kernel indexed local arrays with values LOADED from the
// constexpr Cayley tables (mx[TAB.t1_dst[ie][ip]] += ...). SROA runs before
// full unrolling, so mx[]/v[] were never promoted to registers -> scratch
// traffic (~2.7 GB) explains the 2-3x gap over the HBM roofline. This version
// makes every index a TEMPLATE PARAMETER (syntactically constant before any
// optimization), guaranteeing full register promotion; the +/-1 signs fold
// into FMA input-negate modifiers (free on VOP3).

namespace cga {

__host__ __device__ constexpr int popc5(int x) {
    int c = 0;
    for (int i = 0; i < 5; ++i) c += (x >> i) & 1;
    return c;
}
__host__ __device__ constexpr int blade_of_even(int idx) {
    int cnt = 0;
    for (int b = 0; b < 32; ++b)
        if ((popc5(b) & 1) == 0) { if (cnt == idx) return b; ++cnt; }
    return 0;
}
__host__ __device__ constexpr int blade_of_odd(int idx) {
    int cnt = 0;
    for (int b = 0; b < 32; ++b)
        if ((popc5(b) & 1) == 1) { if (cnt == idx) return b; ++cnt; }
    return 0;
}
__host__ __device__ constexpr int even_index(int blade) {
    int idx = 0;
    for (int b = 0; b < blade; ++b) if ((popc5(b) & 1) == 0) ++idx;
    return idx;
}
__host__ __device__ constexpr int odd_index(int blade) {
    int idx = 0;
    for (int b = 0; b < blade; ++b) if ((popc5(b) & 1) == 1) ++idx;
    return idx;
}
// Sign of basis-blade product a*b (reorder sign + metric; e5 = bit4 squares -1).
__host__ __device__ constexpr int mul_sign(int a, int b) {
    int s = 0;
    for (int t = a >> 1; t; t >>= 1) s += popc5(t & b);
    int sign = (s & 1) ? -1 : 1;
    if ((a & b) & 16) sign = -sign;
    return sign;
}
__host__ __device__ constexpr int rev_sign(int b) {
    int g = popc5(b);
    return ((g * (g - 1) / 2) & 1) ? -1 : 1;
}

struct Tables {
    int t1_dst[16][5];  // odd-blade index of EVEN[ie] * G1[ip]
    int t1_sgn[16][5];
    int t2_e[16][5];    // even index e s.t. ODD[io] * EVEN[e] -> G1[iq]
    int t2_sgn[16][5];  // includes reverse sign of EVEN[e]
};

__host__ __device__ constexpr Tables make_tables() {
    Tables r{};
    for (int ie = 0; ie < 16; ++ie) {
        const int a = blade_of_even(ie);
        for (int ip = 0; ip < 5; ++ip) {
            const int b = 1 << ip;
            const int c = a ^ b;
            r.t1_dst[ie][ip] = odd_index(c);
            r.t1_sgn[ie][ip] = mul_sign(a, b);
        }
    }
    for (int io = 0; io < 16; ++io) {
        const int a = blade_of_odd(io);
        for (int iq = 0; iq < 5; ++iq) {
            const int c = 1 << iq;
            const int b = a ^ c;          // connecting blade: always even grade
            r.t2_e[io][iq]   = even_index(b);
            r.t2_sgn[io][iq] = mul_sign(a, b) * rev_sign(b);
        }
    }
    return r;
}

constexpr Tables TAB = make_tables();

}  // namespace cga

// ---- template-unrolled sparse contractions: every index is a compile-time
// constant BEFORE any optimization pass runs -> guaranteed SROA/reg promotion.

template <int IE, int IP>
__device__ __forceinline__ void t1_term(const float (&v)[16], const float (&p)[5],
                                        float (&mx)[16]) {
    constexpr int dst = cga::TAB.t1_dst[IE][IP];
    constexpr int sgn = cga::TAB.t1_sgn[IE][IP];
    if constexpr (sgn >= 0) mx[dst] = __builtin_fmaf( v[IE], p[IP], mx[dst]);
    else                    mx[dst] = __builtin_fmaf(-v[IE], p[IP], mx[dst]);
}

template <std::size_t... I>
__device__ __forceinline__ void t1_all(const float (&v)[16], const float (&p)[5],
                                       float (&mx)[16], std::index_sequence<I...>) {
    (t1_term<(int)(I / 5), (int)(I % 5)>(v, p, mx), ...);
}

template <int IO, int IQ>
__device__ __forceinline__ void t2_term(const float (&v)[16], const float (&mx)[16],
                                        float (&q)[5]) {
    constexpr int e   = cga::TAB.t2_e[IO][IQ];
    constexpr int sgn = cga::TAB.t2_sgn[IO][IQ];
    if constexpr (sgn >= 0) q[IQ] = __builtin_fmaf( mx[IO], v[e], q[IQ]);
    else                    q[IQ] = __builtin_fmaf(-mx[IO], v[e], q[IQ]);
}

template <std::size_t... I>
__device__ __forceinline__ void t2_all(const float (&v)[16], const float (&mx)[16],
                                       float (&q)[5], std::index_sequence<I...>) {
    (t2_term<(int)(I / 5), (int)(I % 5)>(v, mx, q), ...);
}

__global__ __launch_bounds__(256) void cga_sandwich_kernel(
    const float* __restrict__ versor,
    const float* __restrict__ x,
    float* __restrict__ out,
    int n)
{
    const int i = blockIdx.x * blockDim.x + threadIdx.x;
    if (i >= n) return;

    // ---- load 16-component even versor via 4x float4 (64 B/thread) ----
    const float4* v4 = reinterpret_cast<const float4*>(versor) + (size_t)i * 4;
    const float4 a0 = v4[0], a1 = v4[1], a2 = v4[2], a3 = v4[3];
    const float v[16] = {a0.x, a0.y, a0.z, a0.w,
                         a1.x, a1.y, a1.z, a1.w,
                         a2.x, a2.y, a2.z, a2.w,
                         a3.x, a3.y, a3.z, a3.w};

    // ---- encode: P = (x, 0.5|x|^2 - 0.5, 0.5|x|^2 + 0.5) ----
    const float x0 = x[(size_t)3 * i + 0];
    const float x1 = x[(size_t)3 * i + 1];
    const float x2 = x[(size_t)3 * i + 2];
    const float hs = 0.5f * (x0 * x0 + x1 * x1 + x2 * x2);
    const float p[5] = {x0, x1, x2, hs - 0.5f, hs + 0.5f};

    // ---- mx = V * P  (even * grade1 -> odd, 80 FMAs, all in VGPRs) ----
    float mx[16] = {};
    t1_all(v, p, mx, std::make_index_sequence<16 * 5>{});

    // ---- q = mx * ~V  (odd * reversed-even -> grade-1, 80 FMAs) ----
    float q[5] = {};
    t2_all(v, mx, q, std::make_index_sequence<16 * 5>{});

    // ---- decode: scale = q[e5] - q[e4]; out = q_xyz / scale ----
    const float scale = q[4] - q[3];
    const float inv = 1.0f / scale;
    out[(size_t)3 * i + 0] = q[0] * inv;
    out[(size_t)3 * i + 1] = q[1] * inv;
    out[(size_t)3 * i + 2] = q[2] * inv;
}

extern "C" void kernel_launch(void* const* d_in, const int* in_sizes, int n_in,
                              void* d_out, int out_size, void* d_ws, size_t ws_size,
                              hipStream_t stream) {
    const float* versor = (const float*)d_in[0];  // (N, 16) fp32
    const float* x      = (const float*)d_in[1];  // (N, 3)  fp32
    float* out          = (float*)d_out;          // (N, 3)  fp32
    const int n = in_sizes[0] / 16;

    const int block = 256;
    const int grid  = (n + block - 1) / block;
    cga_sandwich_kernel<<<grid, block, 0, stream>>>(versor, x, out, n);
}

// Round 3
// 209.771 us; speedup vs baseline: 1.0009x; 1.0008x over previous
//
#include <hip/hip_runtime.h>
#include <utility>

// CGA Cl(4,1) sandwich pipeline: out = decode( V * encode(x) * ~V ), per point.
// HBM floor: 88 B/point * 2^21 = 184.5 MB -> ~27-29 us at achievable BW.
//
// R3 change: fix global-memory request density. R1/R2 loaded each thread's
// versor as 4x float4 at 64-B lane stride -> each wave instruction touched 32
// cache lines using 32 B of each (4x L1 transaction amplification on the
// 134 MB dominant stream); x/out were 4-B scalar at 12-B stride. This version
// stages everything through LDS so EVERY global access is a dense 16 B/lane
// contiguous float4:
//   - versor: 4 dense float4 loads/thread -> component-major LDS, XOR-swizzled
//     (writes 2-way aliased = free per m136; reads conflict-free)
//   - x: dense float4 loads (192/256 threads) -> LDS -> 3x b32 reads (free)
//   - out: 3x b32 LDS writes (free) -> dense float4 stores (192/256 threads)
// Sparse Cayley contraction unchanged from R2 (template-unrolled, all regs).

namespace cga {

__host__ __device__ constexpr int popc5(int x) {
    int c = 0;
    for (int i = 0; i < 5; ++i) c += (x >> i) & 1;
    return c;
}
__host__ __device__ constexpr int blade_of_even(int idx) {
    int cnt = 0;
    for (int b = 0; b < 32; ++b)
        if ((popc5(b) & 1) == 0) { if (cnt == idx) return b; ++cnt; }
    return 0;
}
__host__ __device__ constexpr int blade_of_odd(int idx) {
    int cnt = 0;
    for (int b = 0; b < 32; ++b)
        if ((popc5(b) & 1) == 1) { if (cnt == idx) return b; ++cnt; }
    return 0;
}
__host__ __device__ constexpr int even_index(int blade) {
    int idx = 0;
    for (int b = 0; b < blade; ++b) if ((popc5(b) & 1) == 0) ++idx;
    return idx;
}
__host__ __device__ constexpr int odd_index(int blade) {
    int idx = 0;
    for (int b = 0; b < blade; ++b) if ((popc5(b) & 1) == 1) ++idx;
    return idx;
}
__host__ __device__ constexpr int mul_sign(int a, int b) {
    int s = 0;
    for (int t = a >> 1; t; t >>= 1) s += popc5(t & b);
    int sign = (s & 1) ? -1 : 1;
    if ((a & b) & 16) sign = -sign;   // shared e5 squares to -1
    return sign;
}
__host__ __device__ constexpr int rev_sign(int b) {
    int g = popc5(b);
    return ((g * (g - 1) / 2) & 1) ? -1 : 1;
}

struct Tables {
    int t1_dst[16][5];
    int t1_sgn[16][5];
    int t2_e[16][5];
    int t2_sgn[16][5];
};

__host__ __device__ constexpr Tables make_tables() {
    Tables r{};
    for (int ie = 0; ie < 16; ++ie) {
        const int a = blade_of_even(ie);
        for (int ip = 0; ip < 5; ++ip) {
            const int b = 1 << ip;
            const int c = a ^ b;
            r.t1_dst[ie][ip] = odd_index(c);
            r.t1_sgn[ie][ip] = mul_sign(a, b);
        }
    }
    for (int io = 0; io < 16; ++io) {
        const int a = blade_of_odd(io);
        for (int iq = 0; iq < 5; ++iq) {
            const int c = 1 << iq;
            const int b = a ^ c;   // connecting blade: always even grade
            r.t2_e[io][iq]   = even_index(b);
            r.t2_sgn[io][iq] = mul_sign(a, b) * rev_sign(b);
        }
    }
    return r;
}

constexpr Tables TAB = make_tables();

}  // namespace cga

template <int IE, int IP>
__device__ __forceinline__ void t1_term(const float (&v)[16], const float (&p)[5],
                                        float (&mx)[16]) {
    constexpr int dst = cga::TAB.t1_dst[IE][IP];
    constexpr int sgn = cga::TAB.t1_sgn[IE][IP];
    if constexpr (sgn >= 0) mx[dst] = __builtin_fmaf( v[IE], p[IP], mx[dst]);
    else                    mx[dst] = __builtin_fmaf(-v[IE], p[IP], mx[dst]);
}
template <std::size_t... I>
__device__ __forceinline__ void t1_all(const float (&v)[16], const float (&p)[5],
                                       float (&mx)[16], std::index_sequence<I...>) {
    (t1_term<(int)(I / 5), (int)(I % 5)>(v, p, mx), ...);
}
template <int IO, int IQ>
__device__ __forceinline__ void t2_term(const float (&v)[16], const float (&mx)[16],
                                        float (&q)[5]) {
    constexpr int e   = cga::TAB.t2_e[IO][IQ];
    constexpr int sgn = cga::TAB.t2_sgn[IO][IQ];
    if constexpr (sgn >= 0) q[IQ] = __builtin_fmaf( mx[IO], v[e], q[IQ]);
    else                    q[IQ] = __builtin_fmaf(-mx[IO], v[e], q[IQ]);
}
template <std::size_t... I>
__device__ __forceinline__ void t2_all(const float (&v)[16], const float (&mx)[16],
                                       float (&q)[5], std::index_sequence<I...>) {
    (t2_term<(int)(I / 5), (int)(I % 5)>(v, mx, q), ...);
}

__device__ __forceinline__ void cga_compute(const float (&v)[16],
                                            float x0, float x1, float x2,
                                            float& o0, float& o1, float& o2) {
    const float hs = 0.5f * (x0 * x0 + x1 * x1 + x2 * x2);
    const float p[5] = {x0, x1, x2, hs - 0.5f, hs + 0.5f};
    float mx[16] = {};
    t1_all(v, p, mx, std::make_index_sequence<16 * 5>{});
    float q[5] = {};
    t2_all(v, mx, q, std::make_index_sequence<16 * 5>{});
    const float inv = 1.0f / (q[4] - q[3]);
    o0 = q[0] * inv;
    o1 = q[1] * inv;
    o2 = q[2] * inv;
}

// ---- tiled kernel: 256 points per 256-thread block, all-dense global I/O ----
// Requires n % 256 == 0 (true for this problem: n = 2^21).
__global__ __launch_bounds__(256) void cga_tiled_kernel(
    const float* __restrict__ versor,
    const float* __restrict__ x,
    float* __restrict__ out)
{
    __shared__ float lds_v[16 * 256];  // component-major, XOR-swizzled
    __shared__ float lds_x[3 * 256];
    __shared__ float lds_o[3 * 256];

    const int t   = threadIdx.x;
    const int blk = blockIdx.x;

    // ---- dense cooperative loads (16 B/lane contiguous) ----
    const float4* vg = reinterpret_cast<const float4*>(versor);
    float4 f[4];
#pragma unroll
    for (int j = 0; j < 4; ++j)
        f[j] = vg[(size_t)blk * 1024 + (size_t)(j * 256 + t)];

    float4 xf = make_float4(0.f, 0.f, 0.f, 0.f);
    if (t < 192)
        xf = reinterpret_cast<const float4*>(x)[(size_t)blk * 192 + t];

    // ---- scatter versor float4s to component-major LDS ----
    // global float4 (j*256+t) = flat floats [1024j+4t, +4) = point p = 64j+t/4,
    // comps c = 4*(t&3)+w. LDS word for (c,p): c*256 + (p ^ (4*(c&7))).
    // Write bank = ((t>>2) ^ (4w + 16*(t&1... (b&1)))) -> all 32 banks, 2-way: free.
    {
        const int b = t & 3;
        const int a = t >> 2;
#pragma unroll
        for (int j = 0; j < 4; ++j) {
            const int p = 64 * j + a;
            const float w4[4] = {f[j].x, f[j].y, f[j].z, f[j].w};
#pragma unroll
            for (int w = 0; w < 4; ++w) {
                const int c = 4 * b + w;
                lds_v[c * 256 + (p ^ (4 * (c & 7)))] = w4[w];
            }
        }
    }
    if (t < 192)
        reinterpret_cast<float4*>(lds_x)[t] = xf;

    __syncthreads();

    // ---- per-thread gather (conflict-free) + compute ----
    float v[16];
#pragma unroll
    for (int c = 0; c < 16; ++c)
        v[c] = lds_v[c * 256 + (t ^ (4 * (c & 7)))];

    const float x0 = lds_x[3 * t + 0];
    const float x1 = lds_x[3 * t + 1];
    const float x2 = lds_x[3 * t + 2];

    float o0, o1, o2;
    cga_compute(v, x0, x1, x2, o0, o1, o2);

    lds_o[3 * t + 0] = o0;
    lds_o[3 * t + 1] = o1;
    lds_o[3 * t + 2] = o2;

    __syncthreads();

    // ---- dense cooperative store ----
    if (t < 192) {
        const float4 ov = reinterpret_cast<const float4*>(lds_o)[t];
        reinterpret_cast<float4*>(out)[(size_t)blk * 192 + t] = ov;
    }
}

// ---- fallback for n not divisible by 256 (not hit for this problem) ----
__global__ __launch_bounds__(256) void cga_simple_kernel(
    const float* __restrict__ versor,
    const float* __restrict__ x,
    float* __restrict__ out,
    int n)
{
    const int i = blockIdx.x * blockDim.x + threadIdx.x;
    if (i >= n) return;
    const float4* v4 = reinterpret_cast<const float4*>(versor) + (size_t)i * 4;
    const float4 a0 = v4[0], a1 = v4[1], a2 = v4[2], a3 = v4[3];
    const float v[16] = {a0.x, a0.y, a0.z, a0.w, a1.x, a1.y, a1.z, a1.w,
                         a2.x, a2.y, a2.z, a2.w, a3.x, a3.y, a3.z, a3.w};
    float o0, o1, o2;
    cga_compute(v, x[(size_t)3 * i], x[(size_t)3 * i + 1], x[(size_t)3 * i + 2],
                o0, o1, o2);
    out[(size_t)3 * i + 0] = o0;
    out[(size_t)3 * i + 1] = o1;
    out[(size_t)3 * i + 2] = o2;
}

extern "C" void kernel_launch(void* const* d_in, const int* in_sizes, int n_in,
                              void* d_out, int out_size, void* d_ws, size_t ws_size,
                              hipStream_t stream) {
    const float* versor = (const float*)d_in[0];  // (N, 16) fp32
    const float* x      = (const float*)d_in[1];  // (N, 3)  fp32
    float* out          = (float*)d_out;          // (N, 3)  fp32
    const int n = in_sizes[0] / 16;

    if ((n & 255) == 0) {
        cga_tiled_kernel<<<n / 256, 256, 0, stream>>>(versor, x, out);
    } else {
        cga_simple_kernel<<<(n + 255) / 256, 256, 0, stream>>>(versor, x, out, n);
    }
}